// Round 5
// baseline (78.371 us; speedup 1.0000x reference)
//
#include <hip/hip_runtime.h>
#include <hip/hip_fp16.h>

// SH message-passing inner product:
//   out[e][l] = sum_{j in [l*l, (l+1)^2-1]} sh[row[e]][j] * sh[col[e]][j]
// SH_DIM = 64 (LMAX=7), 8 output irreps per edge.
//
// Round-5: f16 gather table (12.8 MB, row = 128B = 1 line) + software
// pipelining: tile t+1's gathers are issued into registers BEFORE phase B of
// tile t (2x outstanding loads per wave), nontemporal loads for the
// stream-once edge list and nontemporal stores for the output (keep L2 for
// the gather working set).
//
// One wave = 64 edges, 4 tiles of 16.
//  Phase A: lane (gid=lane>>4, s=lane&15) holds the 8B chunk s of rows
//           row/col of edge et=g4*4+gid (prefetched), cvt f16->f32, product,
//           ds_write_b128 at chunk slot s^(et&15).
//  Phase B: lane (eb=lane&15, q=lane>>4) reads its 16 features via 4x
//           ds_read_b128 (slot k^(eb&15)), reduces irrep segments in regs,
//           one __shfl fixes blocks crossing features 32/48, nt-stores direct.

#define WPB 4

__global__ __launch_bounds__(256) void cvt_f16_kernel(
    const float* __restrict__ in, __half* __restrict__ out, const int n8)
{
    const int i = blockIdx.x * 256 + threadIdx.x;   // 8 floats per thread
    if (i < n8) {
        const float4 x = ((const float4*)in)[i * 2];
        const float4 y = ((const float4*)in)[i * 2 + 1];
        union { __half h[8]; float4 f; } u;
        u.h[0] = __float2half_rn(x.x); u.h[1] = __float2half_rn(x.y);
        u.h[2] = __float2half_rn(x.z); u.h[3] = __float2half_rn(x.w);
        u.h[4] = __float2half_rn(y.x); u.h[5] = __float2half_rn(y.y);
        u.h[6] = __float2half_rn(y.z); u.h[7] = __float2half_rn(y.w);
        ((float4*)out)[i] = u.f;
    }
}

struct TileRegs {
    float2 a[4];
    float2 b[4];
};

__global__ __launch_bounds__(WPB * 64, 6) void sh_msg_f16_kernel(
    const int*   __restrict__ row,
    const int*   __restrict__ col,
    const __half* __restrict__ tbl,   // [N][64] f16, row = 128 B
    float*       __restrict__ out,
    const int E)
{
    __shared__ float tile[WPB][16 * 64];

    const int lane = threadIdx.x & 63;
    const int wid  = threadIdx.x >> 6;
    const long e0l = ((long)blockIdx.x * WPB + wid) * 64;
    if (e0l >= E) return;
    const int e0 = (int)e0l;

    const int gid = lane >> 4;                // phase-A edge-within-group
    const int s   = lane & 15;                // phase-A 8B chunk within row
    const unsigned fo8 = (unsigned)(s << 3);  // byte offset within 128B row

    const char* __restrict__ tblb = (const char*)tbl;
    float* __restrict__ tw = tile[wid];

    const int eb = s;                         // phase-B edge-in-tile
    const int q  = gid;                       // phase-B feature quarter

    // ---- tile gather: issue 8B loads for 16 edges (4 per lane-group) ----
    auto load_tile = [&](int tb) -> TileRegs {
        TileRegs tr;
        #pragma unroll
        for (int g4 = 0; g4 < 4; ++g4) {
            int e = tb + g4 * 4 + gid;
            e = (e < E) ? e : (E - 1);        // clamp (stores are guarded)
            const size_t ia = (size_t)(unsigned)__builtin_nontemporal_load(row + e);
            const size_t ib = (size_t)(unsigned)__builtin_nontemporal_load(col + e);
            tr.a[g4] = *(const float2*)(tblb + (ia << 7) + fo8);
            tr.b[g4] = *(const float2*)(tblb + (ib << 7) + fo8);
        }
        return tr;
    };

    TileRegs cur = load_tile(e0);

    #pragma unroll
    for (int t = 0; t < 4; ++t) {
        const int tb = e0 + t * 16;

        // ---------- phase A: cvt + product + LDS write ----------
        #pragma unroll
        for (int g4 = 0; g4 < 4; ++g4) {
            const int et = g4 * 4 + gid;
            const float2 fa0 = __half22float2(*(const __half2*)&cur.a[g4].x);
            const float2 fa1 = __half22float2(*(const __half2*)&cur.a[g4].y);
            const float2 fb0 = __half22float2(*(const __half2*)&cur.b[g4].x);
            const float2 fb1 = __half22float2(*(const __half2*)&cur.b[g4].y);
            float4 p;
            p.x = fa0.x * fb0.x; p.y = fa0.y * fb0.y;
            p.z = fa1.x * fb1.x; p.w = fa1.y * fb1.y;
            const int c = s ^ (et & 15);      // swizzled chunk slot
            *(float4*)(tw + et * 64 + (c << 2)) = p;
        }

        // ---------- prefetch next tile (overlaps phase B) ----------
        TileRegs nxt;
        if (t < 3) nxt = load_tile(e0 + (t + 1) * 16);

        // ---------- phase B: transpose read + reduce + store ----------
        float v[16];
        #pragma unroll
        for (int j = 0; j < 4; ++j) {
            const int k = q * 4 + j;
            const int c = k ^ (eb & 15);      // un-swizzle
            const float4 w = *(const float4*)(tw + eb * 64 + (c << 2));
            v[j * 4 + 0] = w.x; v[j * 4 + 1] = w.y;
            v[j * 4 + 2] = w.z; v[j * 4 + 3] = w.w;
        }

        const float t13  = v[1] + v[2] + v[3];
        const float t48  = ((v[4] + v[5]) + (v[6] + v[7])) + v[8];
        const float t915 = ((v[9] + v[10]) + (v[11] + v[12]))
                         + ((v[13] + v[14]) + v[15]);

        float exp_val = 0.0f;
        if (q == 2) exp_val = v[0] + t13;     // exports feats 32..35
        if (q == 3) exp_val = v[0];           // exports feat 48
        const float got = __shfl(exp_val, (lane + 16) & 63, 64);

        const int e = tb + eb;
        if (e < E) {
            float* o = out + (long)e * 8;
            if (q == 0) {
                // l=0:[0]  l=1:[1..3]  l=2:[4..8]  l=3:[9..15]
                __builtin_nontemporal_store(v[0], o + 0);
                __builtin_nontemporal_store(t13,  o + 1);
                __builtin_nontemporal_store(t48,  o + 2);
                __builtin_nontemporal_store(t915, o + 3);
            } else if (q == 1) {
                __builtin_nontemporal_store((v[0] + t13) + t48, o + 4);
                __builtin_nontemporal_store(t915 + got,         o + 5);
            } else if (q == 2) {
                __builtin_nontemporal_store((t48 + t915) + got, o + 6);
            } else {
                __builtin_nontemporal_store((t13 + t48) + t915, o + 7);
            }
        }

        cur = nxt;
    }
}

// f32 fallback (ws too small): no f16 table.
__global__ __launch_bounds__(WPB * 64, 6) void sh_msg_f32_kernel(
    const int*   __restrict__ row,
    const int*   __restrict__ col,
    const float* __restrict__ sh,
    float*       __restrict__ out,
    const int E)
{
    __shared__ float tile[WPB][16 * 64];
    const int lane = threadIdx.x & 63;
    const int wid  = threadIdx.x >> 6;
    const long e0l = ((long)blockIdx.x * WPB + wid) * 64;
    if (e0l >= E) return;
    const int e0 = (int)e0l;
    const int gid = lane >> 4;
    const int s   = lane & 15;
    const unsigned fo = (unsigned)(s << 4);
    const char* __restrict__ shb = (const char*)sh;
    float* __restrict__ tw = tile[wid];
    const int eb = s;
    const int q  = gid;

    #pragma unroll
    for (int t = 0; t < 4; ++t) {
        const int tb = e0 + t * 16;
        #pragma unroll
        for (int g4 = 0; g4 < 4; ++g4) {
            const int et = g4 * 4 + gid;
            int e = tb + et;
            e = (e < E) ? e : (E - 1);
            const size_t ia = (size_t)(unsigned)row[e];
            const size_t ib = (size_t)(unsigned)col[e];
            const float4 a = *(const float4*)(shb + (ia << 8) + fo);
            const float4 b = *(const float4*)(shb + (ib << 8) + fo);
            float4 p;
            p.x = a.x * b.x; p.y = a.y * b.y;
            p.z = a.z * b.z; p.w = a.w * b.w;
            const int c = s ^ (et & 15);
            *(float4*)(tw + et * 64 + (c << 2)) = p;
        }
        float v[16];
        #pragma unroll
        for (int j = 0; j < 4; ++j) {
            const int k = q * 4 + j;
            const int c = k ^ (eb & 15);
            const float4 w = *(const float4*)(tw + eb * 64 + (c << 2));
            v[j * 4 + 0] = w.x; v[j * 4 + 1] = w.y;
            v[j * 4 + 2] = w.z; v[j * 4 + 3] = w.w;
        }
        const float t13  = v[1] + v[2] + v[3];
        const float t48  = ((v[4] + v[5]) + (v[6] + v[7])) + v[8];
        const float t915 = ((v[9] + v[10]) + (v[11] + v[12]))
                         + ((v[13] + v[14]) + v[15]);
        float exp_val = 0.0f;
        if (q == 2) exp_val = v[0] + t13;
        if (q == 3) exp_val = v[0];
        const float got = __shfl(exp_val, (lane + 16) & 63, 64);
        const int e = tb + eb;
        if (e < E) {
            float* o = out + (long)e * 8;
            if (q == 0)      *(float4*)o = make_float4(v[0], t13, t48, t915);
            else if (q == 1) *(float2*)(o + 4) = make_float2((v[0] + t13) + t48, t915 + got);
            else if (q == 2) o[6] = (t48 + t915) + got;
            else             o[7] = (t13 + t48) + t915;
        }
    }
}

extern "C" void kernel_launch(void* const* d_in, const int* in_sizes, int n_in,
                              void* d_out, int out_size, void* d_ws, size_t ws_size,
                              hipStream_t stream) {
    const int* edge_index = (const int*)d_in[0];   // [2, E] int32
    const float* node_sh  = (const float*)d_in[1]; // [N, 64] f32
    float* out            = (float*)d_out;         // [E, 8] f32

    const int E = in_sizes[0] / 2;
    const int nsh = in_sizes[1];                   // N * 64 floats
    const int* row = edge_index;
    const int* col = edge_index + E;

    const int edges_per_block = WPB * 64;
    const int blocks = (E + edges_per_block - 1) / edges_per_block;

    const size_t need = (size_t)nsh * sizeof(__half);
    if (ws_size >= need) {
        __half* tbl = (__half*)d_ws;
        const int n8 = nsh / 8;
        cvt_f16_kernel<<<(n8 + 255) / 256, 256, 0, stream>>>(node_sh, tbl, n8);
        sh_msg_f16_kernel<<<blocks, WPB * 64, 0, stream>>>(row, col, tbl, out, E);
    } else {
        sh_msg_f32_kernel<<<blocks, WPB * 64, 0, stream>>>(row, col, node_sh, out, E);
    }
}

// Round 7
// 72.725 us; speedup vs baseline: 1.0776x; 1.0776x over previous
//
#include <hip/hip_runtime.h>
#include <hip/hip_fp16.h>

// SH message-passing inner product:
//   out[e][l] = sum_{j in [l*l, (l+1)^2-1]} sh[row[e]][j] * sh[col[e]][j]
// SH_DIM = 64 (LMAX=7), 8 output irreps per edge.
//
// Round-7 = round-4 config (best measured, 68.2 us total), with the nt-load
// compile fix (clang ext_vector_type instead of HIP float4 class).
// Round-5 established the kernel is external-byte-bound at ~3.5 TB/s:
// duration tracks (FETCH+WRITE) linearly across 4 structures.
// Byte budget: gathers ~156 + idx 12.8 + out 50 + cvt 38.4 ~= 257 MB ~= 68 us.
//
// Main kernel: one wave = 64 edges, 4 tiles of 16.
//  Phase A: lane (gid=lane>>4, s=lane&15) loads the 8B chunk s of rows
//           row/col of edge et=g4*4+gid (one dwordx2 covers 4 rows per
//           instr), f16->f32, product, ds_write_b128 at slot s^(et&15).
//  Phase B: lane (eb=lane&15, q=lane>>4) reads its 16 features via 4x
//           ds_read_b128 (slot k^(eb&15)), reduces irrep segments in regs,
//           one __shfl fixes the two blocks crossing features 32/48,
//           vectorized cached stores.

#define WPB 4

typedef float vfloat4 __attribute__((ext_vector_type(4)));

__global__ __launch_bounds__(256) void cvt_f16_kernel(
    const float* __restrict__ in, __half* __restrict__ out, const int n8)
{
    const int i = blockIdx.x * 256 + threadIdx.x;   // 8 floats per thread
    if (i < n8) {
        // stream-once source: nt loads keep L2 free for the table itself
        const vfloat4 x = __builtin_nontemporal_load((const vfloat4*)in + i * 2);
        const vfloat4 y = __builtin_nontemporal_load((const vfloat4*)in + i * 2 + 1);
        union { __half h[8]; vfloat4 f; } u;
        u.h[0] = __float2half_rn(x.x); u.h[1] = __float2half_rn(x.y);
        u.h[2] = __float2half_rn(x.z); u.h[3] = __float2half_rn(x.w);
        u.h[4] = __float2half_rn(y.x); u.h[5] = __float2half_rn(y.y);
        u.h[6] = __float2half_rn(y.z); u.h[7] = __float2half_rn(y.w);
        ((vfloat4*)out)[i] = u.f;                   // cached: main kernel reads it
    }
}

__global__ __launch_bounds__(WPB * 64, 6) void sh_msg_f16_kernel(
    const int*   __restrict__ row,
    const int*   __restrict__ col,
    const __half* __restrict__ tbl,   // [N][64] f16, row = 128 B
    float*       __restrict__ out,
    const int E)
{
    __shared__ float tile[WPB][16 * 64];

    const int lane = threadIdx.x & 63;
    const int wid  = threadIdx.x >> 6;
    const long e0l = ((long)blockIdx.x * WPB + wid) * 64;
    if (e0l >= E) return;
    const int e0 = (int)e0l;

    const int gid = lane >> 4;                // phase-A edge-within-group
    const int s   = lane & 15;                // phase-A 8B chunk within row
    const unsigned fo8 = (unsigned)(s << 3);  // byte offset within 128B row

    const char* __restrict__ tblb = (const char*)tbl;
    float* __restrict__ tw = tile[wid];

    const int eb = s;                         // phase-B edge-in-tile
    const int q  = gid;                       // phase-B feature quarter

    #pragma unroll
    for (int t = 0; t < 4; ++t) {
        const int tb = e0 + t * 16;

        // ---------- phase A: gather + cvt + product + LDS write ----------
        #pragma unroll
        for (int g4 = 0; g4 < 4; ++g4) {
            const int et = g4 * 4 + gid;
            int e = tb + et;
            e = (e < E) ? e : (E - 1);        // clamp (stores are guarded)
            const size_t ia = (size_t)(unsigned)row[e];
            const size_t ib = (size_t)(unsigned)col[e];
            const float2 araw = *(const float2*)(tblb + (ia << 7) + fo8);
            const float2 braw = *(const float2*)(tblb + (ib << 7) + fo8);
            const float2 fa0 = __half22float2(*(const __half2*)&araw.x);
            const float2 fa1 = __half22float2(*(const __half2*)&araw.y);
            const float2 fb0 = __half22float2(*(const __half2*)&braw.x);
            const float2 fb1 = __half22float2(*(const __half2*)&braw.y);
            float4 p;
            p.x = fa0.x * fb0.x; p.y = fa0.y * fb0.y;
            p.z = fa1.x * fb1.x; p.w = fa1.y * fb1.y;
            const int c = s ^ (et & 15);      // swizzled chunk slot
            *(float4*)(tw + et * 64 + (c << 2)) = p;
        }

        // ---------- phase B: transpose read + reduce + store ----------
        float v[16];
        #pragma unroll
        for (int j = 0; j < 4; ++j) {
            const int k = q * 4 + j;
            const int c = k ^ (eb & 15);      // un-swizzle
            const float4 w = *(const float4*)(tw + eb * 64 + (c << 2));
            v[j * 4 + 0] = w.x; v[j * 4 + 1] = w.y;
            v[j * 4 + 2] = w.z; v[j * 4 + 3] = w.w;
        }

        const float t13  = v[1] + v[2] + v[3];
        const float t48  = ((v[4] + v[5]) + (v[6] + v[7])) + v[8];
        const float t915 = ((v[9] + v[10]) + (v[11] + v[12]))
                         + ((v[13] + v[14]) + v[15]);

        float exp_val = 0.0f;
        if (q == 2) exp_val = v[0] + t13;     // exports feats 32..35
        if (q == 3) exp_val = v[0];           // exports feat 48
        const float got = __shfl(exp_val, (lane + 16) & 63, 64);

        const int e = tb + eb;
        if (e < E) {
            float* o = out + (long)e * 8;
            if (q == 0) {
                // l=0:[0]  l=1:[1..3]  l=2:[4..8]  l=3:[9..15]
                *(float4*)o = make_float4(v[0], t13, t48, t915);
            } else if (q == 1) {
                // l=4:[16..24] ; l=5:[25..35] = t915 + q2's 32..35
                *(float2*)(o + 4) = make_float2((v[0] + t13) + t48, t915 + got);
            } else if (q == 2) {
                // l=6:[36..48] = t48+t915 + q3's feat 48
                o[6] = (t48 + t915) + got;
            } else {
                // l=7:[49..63]
                o[7] = (t13 + t48) + t915;
            }
        }
    }
}

// f32 fallback (ws too small for the f16 table).
__global__ __launch_bounds__(WPB * 64, 6) void sh_msg_f32_kernel(
    const int*   __restrict__ row,
    const int*   __restrict__ col,
    const float* __restrict__ sh,
    float*       __restrict__ out,
    const int E)
{
    __shared__ float tile[WPB][16 * 64];
    const int lane = threadIdx.x & 63;
    const int wid  = threadIdx.x >> 6;
    const long e0l = ((long)blockIdx.x * WPB + wid) * 64;
    if (e0l >= E) return;
    const int e0 = (int)e0l;
    const int gid = lane >> 4;
    const int s   = lane & 15;
    const unsigned fo = (unsigned)(s << 4);
    const char* __restrict__ shb = (const char*)sh;
    float* __restrict__ tw = tile[wid];
    const int eb = s;
    const int q  = gid;

    #pragma unroll
    for (int t = 0; t < 4; ++t) {
        const int tb = e0 + t * 16;
        #pragma unroll
        for (int g4 = 0; g4 < 4; ++g4) {
            const int et = g4 * 4 + gid;
            int e = tb + et;
            e = (e < E) ? e : (E - 1);
            const size_t ia = (size_t)(unsigned)row[e];
            const size_t ib = (size_t)(unsigned)col[e];
            const float4 a = *(const float4*)(shb + (ia << 8) + fo);
            const float4 b = *(const float4*)(shb + (ib << 8) + fo);
            float4 p;
            p.x = a.x * b.x; p.y = a.y * b.y;
            p.z = a.z * b.z; p.w = a.w * b.w;
            const int c = s ^ (et & 15);
            *(float4*)(tw + et * 64 + (c << 2)) = p;
        }
        float v[16];
        #pragma unroll
        for (int j = 0; j < 4; ++j) {
            const int k = q * 4 + j;
            const int c = k ^ (eb & 15);
            const float4 w = *(const float4*)(tw + eb * 64 + (c << 2));
            v[j * 4 + 0] = w.x; v[j * 4 + 1] = w.y;
            v[j * 4 + 2] = w.z; v[j * 4 + 3] = w.w;
        }
        const float t13  = v[1] + v[2] + v[3];
        const float t48  = ((v[4] + v[5]) + (v[6] + v[7])) + v[8];
        const float t915 = ((v[9] + v[10]) + (v[11] + v[12]))
                         + ((v[13] + v[14]) + v[15]);
        float exp_val = 0.0f;
        if (q == 2) exp_val = v[0] + t13;
        if (q == 3) exp_val = v[0];
        const float got = __shfl(exp_val, (lane + 16) & 63, 64);
        const int e = tb + eb;
        if (e < E) {
            float* o = out + (long)e * 8;
            if (q == 0)      *(float4*)o = make_float4(v[0], t13, t48, t915);
            else if (q == 1) *(float2*)(o + 4) = make_float2((v[0] + t13) + t48, t915 + got);
            else if (q == 2) o[6] = (t48 + t915) + got;
            else             o[7] = (t13 + t48) + t915;
        }
    }
}

extern "C" void kernel_launch(void* const* d_in, const int* in_sizes, int n_in,
                              void* d_out, int out_size, void* d_ws, size_t ws_size,
                              hipStream_t stream) {
    const int* edge_index = (const int*)d_in[0];   // [2, E] int32
    const float* node_sh  = (const float*)d_in[1]; // [N, 64] f32
    float* out            = (float*)d_out;         // [E, 8] f32

    const int E = in_sizes[0] / 2;
    const int nsh = in_sizes[1];                   // N * 64 floats
    const int* row = edge_index;
    const int* col = edge_index + E;

    const int edges_per_block = WPB * 64;
    const int blocks = (E + edges_per_block - 1) / edges_per_block;

    const size_t need = (size_t)nsh * sizeof(__half);
    if (ws_size >= need) {
        __half* tbl = (__half*)d_ws;
        const int n8 = nsh / 8;
        cvt_f16_kernel<<<(n8 + 255) / 256, 256, 0, stream>>>(node_sh, tbl, n8);
        sh_msg_f16_kernel<<<blocks, WPB * 64, 0, stream>>>(row, col, tbl, out, E);
    } else {
        sh_msg_f32_kernel<<<blocks, WPB * 64, 0, stream>>>(row, col, node_sh, out, E);
    }
}

// Round 8
// 68.205 us; speedup vs baseline: 1.1490x; 1.0663x over previous
//
#include <hip/hip_runtime.h>
#include <hip/hip_fp16.h>

// SH message-passing inner product:
//   out[e][l] = sum_{j in [l*l, (l+1)^2-1]} sh[row[e]][j] * sh[col[e]][j]
// SH_DIM = 64 (LMAX=7), 8 output irreps per edge.
//
// Round-8 = round-4 config exactly (best measured: 68.2 us total).
// Round-7 isolated the cvt nt-load regression (12 us vs 7.7 us) -> plain
// cached loads in the cvt pre-pass.
// Evidence (rounds 2-7): duration tracks (FETCH+WRITE) linearly at a
// ~3.4-3.8 TB/s external-byte wall for this random-gather pattern; the main
// kernel is pinned at 60.5 us with FETCH 156 MB + WRITE 50 MB.
// Byte budget: gathers ~156 + idx 12.8 + out 50 + cvt 38.4 ~= 257 MB ~= 68 us.
//
// Main kernel: one wave = 64 edges, 4 tiles of 16.
//  Phase A: lane (gid=lane>>4, s=lane&15) loads the 8B chunk s of rows
//           row/col of edge et=g4*4+gid (one dwordx2 covers 4 rows per
//           instr, coalesced per 16-lane group), f16->f32, product,
//           ds_write_b128 at swizzled chunk slot s^(et&15).
//  Phase B: lane (eb=lane&15, q=lane>>4) reads its 16 features via 4x
//           ds_read_b128 (slot k^(eb&15)), reduces irrep segments in regs,
//           one __shfl fixes the two blocks crossing features 32/48,
//           vectorized cached stores.

#define WPB 4

__global__ __launch_bounds__(256) void cvt_f16_kernel(
    const float* __restrict__ in, __half* __restrict__ out, const int n8)
{
    const int i = blockIdx.x * 256 + threadIdx.x;   // 8 floats per thread
    if (i < n8) {
        const float4 x = ((const float4*)in)[i * 2];
        const float4 y = ((const float4*)in)[i * 2 + 1];
        union { __half h[8]; float4 f; } u;
        u.h[0] = __float2half_rn(x.x); u.h[1] = __float2half_rn(x.y);
        u.h[2] = __float2half_rn(x.z); u.h[3] = __float2half_rn(x.w);
        u.h[4] = __float2half_rn(y.x); u.h[5] = __float2half_rn(y.y);
        u.h[6] = __float2half_rn(y.z); u.h[7] = __float2half_rn(y.w);
        ((float4*)out)[i] = u.f;                    // cached: main kernel reads it
    }
}

__global__ __launch_bounds__(WPB * 64, 6) void sh_msg_f16_kernel(
    const int*   __restrict__ row,
    const int*   __restrict__ col,
    const __half* __restrict__ tbl,   // [N][64] f16, row = 128 B
    float*       __restrict__ out,
    const int E)
{
    __shared__ float tile[WPB][16 * 64];

    const int lane = threadIdx.x & 63;
    const int wid  = threadIdx.x >> 6;
    const long e0l = ((long)blockIdx.x * WPB + wid) * 64;
    if (e0l >= E) return;
    const int e0 = (int)e0l;

    const int gid = lane >> 4;                // phase-A edge-within-group
    const int s   = lane & 15;                // phase-A 8B chunk within row
    const unsigned fo8 = (unsigned)(s << 3);  // byte offset within 128B row

    const char* __restrict__ tblb = (const char*)tbl;
    float* __restrict__ tw = tile[wid];

    const int eb = s;                         // phase-B edge-in-tile
    const int q  = gid;                       // phase-B feature quarter

    #pragma unroll
    for (int t = 0; t < 4; ++t) {
        const int tb = e0 + t * 16;

        // ---------- phase A: gather + cvt + product + LDS write ----------
        #pragma unroll
        for (int g4 = 0; g4 < 4; ++g4) {
            const int et = g4 * 4 + gid;
            int e = tb + et;
            e = (e < E) ? e : (E - 1);        // clamp (stores are guarded)
            const size_t ia = (size_t)(unsigned)row[e];
            const size_t ib = (size_t)(unsigned)col[e];
            const float2 araw = *(const float2*)(tblb + (ia << 7) + fo8);
            const float2 braw = *(const float2*)(tblb + (ib << 7) + fo8);
            const float2 fa0 = __half22float2(*(const __half2*)&araw.x);
            const float2 fa1 = __half22float2(*(const __half2*)&araw.y);
            const float2 fb0 = __half22float2(*(const __half2*)&braw.x);
            const float2 fb1 = __half22float2(*(const __half2*)&braw.y);
            float4 p;
            p.x = fa0.x * fb0.x; p.y = fa0.y * fb0.y;
            p.z = fa1.x * fb1.x; p.w = fa1.y * fb1.y;
            const int c = s ^ (et & 15);      // swizzled chunk slot
            *(float4*)(tw + et * 64 + (c << 2)) = p;
        }

        // ---------- phase B: transpose read + reduce + store ----------
        float v[16];
        #pragma unroll
        for (int j = 0; j < 4; ++j) {
            const int k = q * 4 + j;
            const int c = k ^ (eb & 15);      // un-swizzle
            const float4 w = *(const float4*)(tw + eb * 64 + (c << 2));
            v[j * 4 + 0] = w.x; v[j * 4 + 1] = w.y;
            v[j * 4 + 2] = w.z; v[j * 4 + 3] = w.w;
        }

        const float t13  = v[1] + v[2] + v[3];
        const float t48  = ((v[4] + v[5]) + (v[6] + v[7])) + v[8];
        const float t915 = ((v[9] + v[10]) + (v[11] + v[12]))
                         + ((v[13] + v[14]) + v[15]);

        float exp_val = 0.0f;
        if (q == 2) exp_val = v[0] + t13;     // exports feats 32..35
        if (q == 3) exp_val = v[0];           // exports feat 48
        const float got = __shfl(exp_val, (lane + 16) & 63, 64);

        const int e = tb + eb;
        if (e < E) {
            float* o = out + (long)e * 8;
            if (q == 0) {
                // l=0:[0]  l=1:[1..3]  l=2:[4..8]  l=3:[9..15]
                *(float4*)o = make_float4(v[0], t13, t48, t915);
            } else if (q == 1) {
                // l=4:[16..24] ; l=5:[25..35] = t915 + q2's 32..35
                *(float2*)(o + 4) = make_float2((v[0] + t13) + t48, t915 + got);
            } else if (q == 2) {
                // l=6:[36..48] = t48+t915 + q3's feat 48
                o[6] = (t48 + t915) + got;
            } else {
                // l=7:[49..63]
                o[7] = (t13 + t48) + t915;
            }
        }
    }
}

// f32 fallback (ws too small for the f16 table).
__global__ __launch_bounds__(WPB * 64, 6) void sh_msg_f32_kernel(
    const int*   __restrict__ row,
    const int*   __restrict__ col,
    const float* __restrict__ sh,
    float*       __restrict__ out,
    const int E)
{
    __shared__ float tile[WPB][16 * 64];
    const int lane = threadIdx.x & 63;
    const int wid  = threadIdx.x >> 6;
    const long e0l = ((long)blockIdx.x * WPB + wid) * 64;
    if (e0l >= E) return;
    const int e0 = (int)e0l;
    const int gid = lane >> 4;
    const int s   = lane & 15;
    const unsigned fo = (unsigned)(s << 4);
    const char* __restrict__ shb = (const char*)sh;
    float* __restrict__ tw = tile[wid];
    const int eb = s;
    const int q  = gid;

    #pragma unroll
    for (int t = 0; t < 4; ++t) {
        const int tb = e0 + t * 16;
        #pragma unroll
        for (int g4 = 0; g4 < 4; ++g4) {
            const int et = g4 * 4 + gid;
            int e = tb + et;
            e = (e < E) ? e : (E - 1);
            const size_t ia = (size_t)(unsigned)row[e];
            const size_t ib = (size_t)(unsigned)col[e];
            const float4 a = *(const float4*)(shb + (ia << 8) + fo);
            const float4 b = *(const float4*)(shb + (ib << 8) + fo);
            float4 p;
            p.x = a.x * b.x; p.y = a.y * b.y;
            p.z = a.z * b.z; p.w = a.w * b.w;
            const int c = s ^ (et & 15);
            *(float4*)(tw + et * 64 + (c << 2)) = p;
        }
        float v[16];
        #pragma unroll
        for (int j = 0; j < 4; ++j) {
            const int k = q * 4 + j;
            const int c = k ^ (eb & 15);
            const float4 w = *(const float4*)(tw + eb * 64 + (c << 2));
            v[j * 4 + 0] = w.x; v[j * 4 + 1] = w.y;
            v[j * 4 + 2] = w.z; v[j * 4 + 3] = w.w;
        }
        const float t13  = v[1] + v[2] + v[3];
        const float t48  = ((v[4] + v[5]) + (v[6] + v[7])) + v[8];
        const float t915 = ((v[9] + v[10]) + (v[11] + v[12]))
                         + ((v[13] + v[14]) + v[15]);
        float exp_val = 0.0f;
        if (q == 2) exp_val = v[0] + t13;
        if (q == 3) exp_val = v[0];
        const float got = __shfl(exp_val, (lane + 16) & 63, 64);
        const int e = tb + eb;
        if (e < E) {
            float* o = out + (long)e * 8;
            if (q == 0)      *(float4*)o = make_float4(v[0], t13, t48, t915);
            else if (q == 1) *(float2*)(o + 4) = make_float2((v[0] + t13) + t48, t915 + got);
            else if (q == 2) o[6] = (t48 + t915) + got;
            else             o[7] = (t13 + t48) + t915;
        }
    }
}

extern "C" void kernel_launch(void* const* d_in, const int* in_sizes, int n_in,
                              void* d_out, int out_size, void* d_ws, size_t ws_size,
                              hipStream_t stream) {
    const int* edge_index = (const int*)d_in[0];   // [2, E] int32
    const float* node_sh  = (const float*)d_in[1]; // [N, 64] f32
    float* out            = (float*)d_out;         // [E, 8] f32

    const int E = in_sizes[0] / 2;
    const int nsh = in_sizes[1];                   // N * 64 floats
    const int* row = edge_index;
    const int* col = edge_index + E;

    const int edges_per_block = WPB * 64;
    const int blocks = (E + edges_per_block - 1) / edges_per_block;

    const size_t need = (size_t)nsh * sizeof(__half);
    if (ws_size >= need) {
        __half* tbl = (__half*)d_ws;
        const int n8 = nsh / 8;
        cvt_f16_kernel<<<(n8 + 255) / 256, 256, 0, stream>>>(node_sh, tbl, n8);
        sh_msg_f16_kernel<<<blocks, WPB * 64, 0, stream>>>(row, col, tbl, out, E);
    } else {
        sh_msg_f32_kernel<<<blocks, WPB * 64, 0, stream>>>(row, col, node_sh, out, E);
    }
}